// Round 2
// baseline (230.564 us; speedup 1.0000x reference)
//
#include <hip/hip_runtime.h>
#include <math.h>

typedef unsigned short u16;
typedef unsigned int u32;
typedef __attribute__((ext_vector_type(8))) short bf16x8;
typedef __attribute__((ext_vector_type(4))) float f32x4;

#define AS1 __attribute__((address_space(1)))
#define AS3 __attribute__((address_space(3)))

static __device__ __forceinline__ u16 f2b(float f) {
  u32 u = __float_as_uint(f);
  return (u16)((u + 0x7FFFu + ((u >> 16) & 1u)) >> 16);
}
static __device__ __forceinline__ u16 f2b_fast(float f) {   // round-half-up
  return (u16)((__float_as_uint(f) + 0x8000u) >> 16);
}
static __device__ __forceinline__ float b2f(u16 b) {
  return __uint_as_float(((u32)b) << 16);
}

// ---------------------------------------------------------------------------
// prep: cast x (4096x1024) -> bf16; P (2048x64) -> bf16 (+ guard row 2048);
//       W (1024x3072) -> Wt bf16 TRANSPOSED [3072][1024] via LDS tiles.
// ---------------------------------------------------------------------------
__global__ __launch_bounds__(256) void prep(
    const float* __restrict__ x, const float* __restrict__ W,
    const float* __restrict__ P,
    u16* __restrict__ xb, u16* __restrict__ Wt, u16* __restrict__ Pb)
{
  __shared__ u16 sT[64 * 68];
  const int bid = blockIdx.x, t = threadIdx.x;
  if (bid < 4096) {
    const size_t base = (size_t)bid * 1024 + t * 4;
    const float4 v = *(const float4*)(x + base);
    const u32 lo = (u32)f2b(v.x) | ((u32)f2b(v.y) << 16);
    const u32 hi = (u32)f2b(v.z) | ((u32)f2b(v.w) << 16);
    *(uint2*)(xb + base) = make_uint2(lo, hi);
  } else if (bid < 4224) {
    const size_t base = (size_t)(bid - 4096) * 1024 + t * 4;
    const float4 v = *(const float4*)(P + base);
    const u32 lo = (u32)f2b(v.x) | ((u32)f2b(v.y) << 16);
    const u32 hi = (u32)f2b(v.z) | ((u32)f2b(v.w) << 16);
    *(uint2*)(Pb + base) = make_uint2(lo, hi);
  } else if (bid < 4992) {
    const int tb = bid - 4224;
    const int tk = tb / 48, tn = tb % 48;
    const int k0 = tk * 64, n0 = tn * 64;
#pragma unroll
    for (int it = 0; it < 4; ++it) {
      const int c = it * 256 + t;
      const int r = c >> 4, c4 = (c & 15) << 2;
      const float4 v = *(const float4*)(W + (size_t)(k0 + r) * 3072 + n0 + c4);
      sT[(c4 + 0) * 68 + r] = f2b(v.x);
      sT[(c4 + 1) * 68 + r] = f2b(v.y);
      sT[(c4 + 2) * 68 + r] = f2b(v.z);
      sT[(c4 + 3) * 68 + r] = f2b(v.w);
    }
    __syncthreads();
#pragma unroll
    for (int it = 0; it < 4; ++it) {
      const int c = it * 256 + t;
      const int rr = c >> 4, k4 = (c & 15) << 2;
      const uint2 rv = *(const uint2*)(sT + rr * 68 + k4);
      *(uint2*)(Wt + (size_t)(n0 + rr) * 1024 + k0 + k4) = rv;
    }
  } else {
    if (t < 64) Pb[2048 * 64 + t] = f2b(P[2047 * 64 + t]);  // guard row
  }
}

// ---------------------------------------------------------------------------
// qkv_gemm (bf16 MFMA): C = xb(4096x1024) @ Wt^T(1024x3072) + bias.
// 128x128 tile, BK=64, XOR-swizzled LDS, global_load_lds 16B, XCD-aware grid.
// Epilogue: LDS repack -> coalesced stores; V goes TRANSPOSED to Vt.
// ---------------------------------------------------------------------------
__global__ __launch_bounds__(256, 3) void qkv_gemm(
    const u16* __restrict__ xb, const u16* __restrict__ Wt,
    const float* __restrict__ bq,
    u16* __restrict__ Qh, u16* __restrict__ Kh, u16* __restrict__ Vt)
{
  __shared__ u16 smem[16384];        // 32 KB: sA | sB, reused as repack tile
  u16* const sA = smem;
  u16* const sB = smem + 8192;
  u16* const T  = smem;              // epilogue tile [64][136]
  const int t = threadIdx.x;
  const int lane = t & 63, w = t >> 6;
  const int l = lane & 15, ql = lane >> 4;
  const int wm = w & 1, wn = w >> 1;
  const int vid = blockIdx.x;
  const int xcd = vid & 7, jj = vid >> 3;          // jj in [0,96)
  const int n0 = (xcd * 3 + (jj % 3)) * 128;
  const int m0 = (jj / 3) * 128;

  f32x4 acc[4][4];
#pragma unroll
  for (int i = 0; i < 4; ++i)
#pragma unroll
    for (int j = 0; j < 4; ++j) acc[i][j] = (f32x4){0.f, 0.f, 0.f, 0.f};

  for (int k0 = 0; k0 < 1024; k0 += 64) {
    __syncthreads();
#pragma unroll
    for (int j = 0; j < 4; ++j) {
      const int ii = w * 4 + j;
      const int m = ii * 8 + (lane >> 3);
      const int q8 = (lane & 7) ^ (m & 7);
      __builtin_amdgcn_global_load_lds(
          (const AS1 u32*)(xb + (size_t)(m0 + m) * 1024 + k0 + q8 * 8),
          (AS3 u32*)(sA + ii * 512), 16, 0, 0);
      __builtin_amdgcn_global_load_lds(
          (const AS1 u32*)(Wt + (size_t)(n0 + m) * 1024 + k0 + q8 * 8),
          (AS3 u32*)(sB + ii * 512), 16, 0, 0);
    }
    __syncthreads();
#pragma unroll
    for (int ks = 0; ks < 2; ++ks) {
      bf16x8 a[4], b[4];
#pragma unroll
      for (int mt = 0; mt < 4; ++mt) {
        const int m = wm * 64 + mt * 16 + l;
        a[mt] = *(const bf16x8*)(sA + m * 64 + (((ks * 4 + ql) ^ (m & 7)) * 8));
      }
#pragma unroll
      for (int nt = 0; nt < 4; ++nt) {
        const int nn = wn * 64 + nt * 16 + l;
        b[nt] = *(const bf16x8*)(sB + nn * 64 + (((ks * 4 + ql) ^ (nn & 7)) * 8));
      }
#pragma unroll
      for (int mt = 0; mt < 4; ++mt)
#pragma unroll
        for (int nt = 0; nt < 4; ++nt)
          acc[mt][nt] = __builtin_amdgcn_mfma_f32_16x16x32_bf16(
              a[mt], b[nt], acc[mt][nt], 0, 0, 0);
    }
  }

  const int which = n0 >> 10;                 // 0=Q 1=K 2=V (uniform per block)
  const int qbase = m0 & 1023;
  const int bb = m0 >> 10;
  const int h0 = (n0 & 1023) >> 6;
#pragma unroll
  for (int pass = 0; pass < 2; ++pass) {
    __syncthreads();
    if (wm == pass) {
#pragma unroll
      for (int nt = 0; nt < 4; ++nt) {
        const int col = wn * 64 + nt * 16 + l;
        const float bias = bq[n0 + col];
#pragma unroll
        for (int mt = 0; mt < 4; ++mt)
#pragma unroll
          for (int rg = 0; rg < 4; ++rg)
            T[(mt * 16 + ql * 4 + rg) * 136 + col] = f2b(acc[mt][nt][rg] + bias);
      }
    }
    __syncthreads();
    if (which < 2) {
      u16* const dst = which ? Kh : Qh;
#pragma unroll
      for (int h = 0; h < 2; ++h) {
        const size_t bnoff = ((size_t)(bb * 16 + h0 + h)) << 16;
#pragma unroll
        for (int it = 0; it < 2; ++it) {
          const int c = it * 256 + t;
          const int r = c >> 3, d8 = (c & 7) * 8;
          const uint4 v = *(const uint4*)(T + r * 136 + h * 64 + d8);
          *(uint4*)(dst + bnoff + ((size_t)(qbase + pass * 64 + r) << 6) + d8) = v;
        }
      }
    } else {
#pragma unroll
      for (int h = 0; h < 2; ++h) {
        const size_t bnoff = ((size_t)(bb * 16 + h0 + h)) << 16;
#pragma unroll
        for (int it = 0; it < 2; ++it) {
          const int c = it * 256 + t;
          const int dr = c >> 3, q8 = (c & 7) * 8;
          u32 pk[4];
#pragma unroll
          for (int e = 0; e < 4; ++e) {
            const u16 lo = T[(q8 + 2 * e + 0) * 136 + h * 64 + dr];
            const u16 hi = T[(q8 + 2 * e + 1) * 136 + h * 64 + dr];
            pk[e] = (u32)lo | ((u32)hi << 16);
          }
          *(uint4*)(Vt + bnoff + ((size_t)dr << 10) + qbase + pass * 64 + q8) =
              make_uint4(pk[0], pk[1], pk[2], pk[3]);
        }
      }
    }
  }
}

// ---------------------------------------------------------------------------
// rel_attn (bf16 MFMA flash, no-max softmax): 128-row q-tile per block,
// 32 rows/wave. THIS ROUND: all operands (Q/K/V/P fragments) read DIRECTLY
// from global (L2-resident: per XCD 8 heads x 256KB KV + 256KB P ~ 2.3MB
// << 4MB L2) -- no LDS staging, no DMA, no ring, and ZERO barriers: every
// wave runs fully decoupled, so dependency-chain latency overlaps freely
// across the 8 resident waves/CU (occupancy is grid-capped at 2 blocks/CU,
// so TLP can't rise -- decoupling is the only latency lever left).
// U/W A-frags built straight into registers from Q/K + rr/rw.
// LDS = 8KB wave-private prob buffer only. V-frag loads hoisted before the
// softmax gather so their L2 latency hides under shfl/exp2.
// ---------------------------------------------------------------------------
__global__ __launch_bounds__(256, 2) void rel_attn(
    const u16* __restrict__ Qh, const u16* __restrict__ Kh,
    const u16* __restrict__ Vt, const u16* __restrict__ Pb,
    const float* __restrict__ rrb, const float* __restrict__ rwb,
    float* __restrict__ out)
{
  __shared__ u16 sProb[4096];        // [128][32] swizzled, wave-private rows

  const int t = threadIdx.x;
  const int lane = t & 63, w = t >> 6;
  const int l = lane & 15, ql = lane >> 4;
  const int vid = blockIdx.x;
  const int qt = vid >> 6, bn = vid & 63;          // vid&7 == bn&7 (XCD)
  const int n = bn & 15, bb = bn >> 4;
  const size_t hoff = (size_t)bn << 16;
  const int q0 = qt << 7;
  const int bz = 6 - 2 * w;                        // z2 rel-tile base

  // A-frags in registers: U = Q + rr, W = Q + rw + K, rows w*32 + mt*16 + l
  bf16x8 au[2][2], aw[2][2];                       // [mt][ks]
#pragma unroll
  for (int mt = 0; mt < 2; ++mt)
#pragma unroll
    for (int ks = 0; ks < 2; ++ks) {
      const int row = w * 32 + mt * 16 + l;
      const int d = ks * 32 + ql * 8;
      const uint4 qv = *(const uint4*)(Qh + hoff + ((size_t)(q0 + row) << 6) + d);
      const uint4 kv = *(const uint4*)(Kh + hoff + ((size_t)(q0 + row) << 6) + d);
      float rv[8], wv[8];
      *(float4*)&rv[0] = *(const float4*)(rrb + n * 64 + d);
      *(float4*)&rv[4] = *(const float4*)(rrb + n * 64 + d + 4);
      *(float4*)&wv[0] = *(const float4*)(rwb + n * 64 + d);
      *(float4*)&wv[4] = *(const float4*)(rwb + n * 64 + d + 4);
      const u16* qp = (const u16*)&qv;
      const u16* kp = (const u16*)&kv;
      u16 uo[8], wo[8];
#pragma unroll
      for (int e = 0; e < 8; ++e) {
        const float qf = b2f(qp[e]);
        uo[e] = f2b(qf + rv[e]);
        wo[e] = f2b(qf + wv[e] + b2f(kp[e]));
      }
      au[mt][ks] = *(const bf16x8*)uo;
      aw[mt][ks] = *(const bf16x8*)wo;
    }

  const f32x4 Z0 = (f32x4){0.f, 0.f, 0.f, 0.f};
  f32x4 o[2][4];
  float lrun[2][4];
#pragma unroll
  for (int mt = 0; mt < 2; ++mt)
#pragma unroll
    for (int ii = 0; ii < 4; ++ii) {
      o[mt][ii] = (f32x4){0.f, 0.f, 0.f, 0.f};
      lrun[mt][ii] = 0.f;
    }

  for (int k0 = 0; k0 < 1024; k0 += 64) {
    const int lbase = 897 + k0 - q0;   // in [1,1857]; max P row touched = 2048

    // z1 = U.K^T, z2 = W.Pband^T -- B-frags straight from L2
    f32x4 z1[2][4], z2[2][5];
    __builtin_amdgcn_s_setprio(1);
#pragma unroll
    for (int ks = 0; ks < 2; ++ks) {
#pragma unroll
      for (int nt = 0; nt < 4; ++nt) {
        const bf16x8 bk = *(const bf16x8*)(
            Kh + hoff + ((size_t)(k0 + nt * 16 + l) << 6) + ks * 32 + ql * 8);
#pragma unroll
        for (int mt = 0; mt < 2; ++mt)
          z1[mt][nt] = __builtin_amdgcn_mfma_f32_16x16x32_bf16(
              au[mt][ks], bk, ks ? z1[mt][nt] : Z0, 0, 0, 0);
      }
      // 6 shared P B-tiles; mt=0 uses rel tiles 1..5, mt=1 uses 0..4
#pragma unroll
      for (int rt = 0; rt < 6; ++rt) {
        const bf16x8 bp = *(const bf16x8*)(
            Pb + ((size_t)(lbase + (bz + rt) * 16 + l) << 6) + ks * 32 + ql * 8);
        if (rt >= 1)
          z2[0][rt - 1] = __builtin_amdgcn_mfma_f32_16x16x32_bf16(
              aw[0][ks], bp, ks ? z2[0][rt - 1] : Z0, 0, 0, 0);
        if (rt <= 4)
          z2[1][rt] = __builtin_amdgcn_mfma_f32_16x16x32_bf16(
              aw[1][ks], bp, ks ? z2[1][rt] : Z0, 0, 0, 0);
      }
    }
    __builtin_amdgcn_s_setprio(0);

    // hoist V-frag loads: their L2 latency hides under the gather/exp2 below
    bf16x8 bvv[2][4];
#pragma unroll
    for (int ks = 0; ks < 2; ++ks)
#pragma unroll
      for (int dt = 0; dt < 4; ++dt)
        bvv[ks][dt] = *(const bf16x8*)(
            Vt + hoff + ((size_t)(dt * 16 + l) << 10) + k0 + ks * 32 + ql * 8);

    // diagonal gather + exp2 (rows i = 32w + 16mt + 4ql + ii)
    float p[2][4][4];
#pragma unroll
    for (int mt = 0; mt < 2; ++mt)
#pragma unroll
      for (int ii = 0; ii < 4; ++ii) {
        const int ci = 15 - ql * 4 - ii;               // c' & 15
        const int src = (lane & 48) | ((l + ci) & 15);
        const bool wrap = l < ci;
#pragma unroll
        for (int jt = 0; jt < 4; ++jt) {
          const float val = wrap ? z2[mt][jt + 1][ii] : z2[mt][jt][ii];
          const float g = __shfl(val, src, 64);
          const float pv =
              __builtin_amdgcn_exp2f((z1[mt][jt][ii] + g) * 0.18033688011112042f);
          p[mt][ii][jt] = pv;
          lrun[mt][ii] += pv;
        }
      }

    // PV in two K=32 steps through the half-tile wave-private prob buffer
#pragma unroll
    for (int ks = 0; ks < 2; ++ks) {
#pragma unroll
      for (int mt = 0; mt < 2; ++mt)
#pragma unroll
        for (int ii = 0; ii < 4; ++ii) {
          const int r = w * 32 + mt * 16 + ql * 4 + ii;
          const int sw2 = (r & 3) ^ ((r >> 2) & 3);
#pragma unroll
          for (int jh = 0; jh < 2; ++jh) {
            const int ch = jh * 2 + (l >> 3);
            sProb[r * 32 + ((ch ^ sw2) * 8) + (l & 7)] =
                f2b_fast(p[mt][ii][ks * 2 + jh]);
          }
        }
      __builtin_amdgcn_s_setprio(1);
#pragma unroll
      for (int mt = 0; mt < 2; ++mt) {
        const int ar = w * 32 + mt * 16 + l;
        const bf16x8 ap = *(const bf16x8*)(
            sProb + ar * 32 + ((ql ^ ((ar & 3) ^ ((ar >> 2) & 3))) * 8));
#pragma unroll
        for (int dt = 0; dt < 4; ++dt)
          o[mt][dt] = __builtin_amdgcn_mfma_f32_16x16x32_bf16(
              ap, bvv[ks][dt], o[mt][dt], 0, 0, 0);
      }
      __builtin_amdgcn_s_setprio(0);
    }
  }

  // epilogue: row-sum reduce, normalize, store fp32 (B, L, D)
#pragma unroll
  for (int mt = 0; mt < 2; ++mt)
#pragma unroll
    for (int ii = 0; ii < 4; ++ii) {
      float ls = lrun[mt][ii];
      ls += __shfl_xor(ls, 1);
      ls += __shfl_xor(ls, 2);
      ls += __shfl_xor(ls, 4);
      ls += __shfl_xor(ls, 8);
      const float inv = 1.f / ls;
      const int q = q0 + w * 32 + mt * 16 + ql * 4 + ii;
#pragma unroll
      for (int dt = 0; dt < 4; ++dt)
        out[((size_t)(bb * 1024 + q) << 10) + (n << 6) + dt * 16 + l] =
            o[mt][dt][ii] * inv;
    }
}

// ---------------------------------------------------------------------------
extern "C" void kernel_launch(void* const* d_in, const int* in_sizes, int n_in,
                              void* d_out, int out_size, void* d_ws, size_t ws_size,
                              hipStream_t stream) {
  const float* x  = (const float*)d_in[0];  // (4,1024,1024)
  const float* P  = (const float*)d_in[1];  // (2048,64)
  const float* Wq = (const float*)d_in[2];  // (1024,3072)
  const float* bq = (const float*)d_in[3];  // (3072,)
  const float* rr = (const float*)d_in[4];  // (16,64)
  const float* rw = (const float*)d_in[5];  // (16,64)
  float* out = (float*)d_out;

  char* ws = (char*)d_ws;
  u16* xb = (u16*)(ws);                      // 8 MB
  u16* Wt = (u16*)(ws + 8388608);            // 6 MB  [3072][1024]
  u16* Pb = (u16*)(ws + 14680064);           // 2049 rows x 64 (+guard)
  u16* Qh = (u16*)(ws + 14946304);           // 8 MB  [bn][q][d]
  u16* Kh = (u16*)(ws + 23334912);           // 8 MB
  u16* Vt = (u16*)(ws + 31723520);           // 8 MB  [bn][d][q]

  prep<<<4993, 256, 0, stream>>>(x, Wq, P, xb, Wt, Pb);
  qkv_gemm<<<768, 256, 0, stream>>>(xb, Wt, bq, Qh, Kh, Vt);
  rel_attn<<<512, 256, 0, stream>>>(Qh, Kh, Vt, Pb, rr, rw, out);
}

// Round 3
// 184.798 us; speedup vs baseline: 1.2477x; 1.2477x over previous
//
#include <hip/hip_runtime.h>
#include <math.h>

typedef unsigned short u16;
typedef unsigned int u32;
typedef __attribute__((ext_vector_type(8))) short bf16x8;
typedef __attribute__((ext_vector_type(4))) float f32x4;

#define AS1 __attribute__((address_space(1)))
#define AS3 __attribute__((address_space(3)))

static __device__ __forceinline__ u16 f2b(float f) {
  u32 u = __float_as_uint(f);
  return (u16)((u + 0x7FFFu + ((u >> 16) & 1u)) >> 16);
}
static __device__ __forceinline__ u16 f2b_fast(float f) {   // round-half-up
  return (u16)((__float_as_uint(f) + 0x8000u) >> 16);
}
static __device__ __forceinline__ float b2f(u16 b) {
  return __uint_as_float(((u32)b) << 16);
}

// ---------------------------------------------------------------------------
// prep: cast x (4096x1024) -> bf16; P (2048x64) -> bf16 (+ guard row 2048);
//       W (1024x3072) -> Wt bf16 TRANSPOSED [3072][1024] via LDS tiles.
// ---------------------------------------------------------------------------
__global__ __launch_bounds__(256) void prep(
    const float* __restrict__ x, const float* __restrict__ W,
    const float* __restrict__ P,
    u16* __restrict__ xb, u16* __restrict__ Wt, u16* __restrict__ Pb)
{
  __shared__ u16 sT[64 * 68];
  const int bid = blockIdx.x, t = threadIdx.x;
  if (bid < 4096) {
    const size_t base = (size_t)bid * 1024 + t * 4;
    const float4 v = *(const float4*)(x + base);
    const u32 lo = (u32)f2b(v.x) | ((u32)f2b(v.y) << 16);
    const u32 hi = (u32)f2b(v.z) | ((u32)f2b(v.w) << 16);
    *(uint2*)(xb + base) = make_uint2(lo, hi);
  } else if (bid < 4224) {
    const size_t base = (size_t)(bid - 4096) * 1024 + t * 4;
    const float4 v = *(const float4*)(P + base);
    const u32 lo = (u32)f2b(v.x) | ((u32)f2b(v.y) << 16);
    const u32 hi = (u32)f2b(v.z) | ((u32)f2b(v.w) << 16);
    *(uint2*)(Pb + base) = make_uint2(lo, hi);
  } else if (bid < 4992) {
    const int tb = bid - 4224;
    const int tk = tb / 48, tn = tb % 48;
    const int k0 = tk * 64, n0 = tn * 64;
#pragma unroll
    for (int it = 0; it < 4; ++it) {
      const int c = it * 256 + t;
      const int r = c >> 4, c4 = (c & 15) << 2;
      const float4 v = *(const float4*)(W + (size_t)(k0 + r) * 3072 + n0 + c4);
      sT[(c4 + 0) * 68 + r] = f2b(v.x);
      sT[(c4 + 1) * 68 + r] = f2b(v.y);
      sT[(c4 + 2) * 68 + r] = f2b(v.z);
      sT[(c4 + 3) * 68 + r] = f2b(v.w);
    }
    __syncthreads();
#pragma unroll
    for (int it = 0; it < 4; ++it) {
      const int c = it * 256 + t;
      const int rr = c >> 4, k4 = (c & 15) << 2;
      const uint2 rv = *(const uint2*)(sT + rr * 68 + k4);
      *(uint2*)(Wt + (size_t)(n0 + rr) * 1024 + k0 + k4) = rv;
    }
  } else {
    if (t < 64) Pb[2048 * 64 + t] = f2b(P[2047 * 64 + t]);  // guard row
  }
}

// ---------------------------------------------------------------------------
// qkv_gemm (bf16 MFMA): C = xb(4096x1024) @ Wt^T(1024x3072) + bias.
// 128x128 tile, BK=64, XOR-swizzled LDS, global_load_lds 16B, XCD-aware grid.
// Epilogue: LDS repack -> coalesced stores; V goes TRANSPOSED to Vt.
// ---------------------------------------------------------------------------
__global__ __launch_bounds__(256, 3) void qkv_gemm(
    const u16* __restrict__ xb, const u16* __restrict__ Wt,
    const float* __restrict__ bq,
    u16* __restrict__ Qh, u16* __restrict__ Kh, u16* __restrict__ Vt)
{
  __shared__ u16 smem[16384];        // 32 KB: sA | sB, reused as repack tile
  u16* const sA = smem;
  u16* const sB = smem + 8192;
  u16* const T  = smem;              // epilogue tile [64][136]
  const int t = threadIdx.x;
  const int lane = t & 63, w = t >> 6;
  const int l = lane & 15, ql = lane >> 4;
  const int wm = w & 1, wn = w >> 1;
  const int vid = blockIdx.x;
  const int xcd = vid & 7, jj = vid >> 3;          // jj in [0,96)
  const int n0 = (xcd * 3 + (jj % 3)) * 128;
  const int m0 = (jj / 3) * 128;

  f32x4 acc[4][4];
#pragma unroll
  for (int i = 0; i < 4; ++i)
#pragma unroll
    for (int j = 0; j < 4; ++j) acc[i][j] = (f32x4){0.f, 0.f, 0.f, 0.f};

  for (int k0 = 0; k0 < 1024; k0 += 64) {
    __syncthreads();
#pragma unroll
    for (int j = 0; j < 4; ++j) {
      const int ii = w * 4 + j;
      const int m = ii * 8 + (lane >> 3);
      const int q8 = (lane & 7) ^ (m & 7);
      __builtin_amdgcn_global_load_lds(
          (const AS1 u32*)(xb + (size_t)(m0 + m) * 1024 + k0 + q8 * 8),
          (AS3 u32*)(sA + ii * 512), 16, 0, 0);
      __builtin_amdgcn_global_load_lds(
          (const AS1 u32*)(Wt + (size_t)(n0 + m) * 1024 + k0 + q8 * 8),
          (AS3 u32*)(sB + ii * 512), 16, 0, 0);
    }
    __syncthreads();
#pragma unroll
    for (int ks = 0; ks < 2; ++ks) {
      bf16x8 a[4], b[4];
#pragma unroll
      for (int mt = 0; mt < 4; ++mt) {
        const int m = wm * 64 + mt * 16 + l;
        a[mt] = *(const bf16x8*)(sA + m * 64 + (((ks * 4 + ql) ^ (m & 7)) * 8));
      }
#pragma unroll
      for (int nt = 0; nt < 4; ++nt) {
        const int nn = wn * 64 + nt * 16 + l;
        b[nt] = *(const bf16x8*)(sB + nn * 64 + (((ks * 4 + ql) ^ (nn & 7)) * 8));
      }
#pragma unroll
      for (int mt = 0; mt < 4; ++mt)
#pragma unroll
        for (int nt = 0; nt < 4; ++nt)
          acc[mt][nt] = __builtin_amdgcn_mfma_f32_16x16x32_bf16(
              a[mt], b[nt], acc[mt][nt], 0, 0, 0);
    }
  }

  const int which = n0 >> 10;                 // 0=Q 1=K 2=V (uniform per block)
  const int qbase = m0 & 1023;
  const int bb = m0 >> 10;
  const int h0 = (n0 & 1023) >> 6;
#pragma unroll
  for (int pass = 0; pass < 2; ++pass) {
    __syncthreads();
    if (wm == pass) {
#pragma unroll
      for (int nt = 0; nt < 4; ++nt) {
        const int col = wn * 64 + nt * 16 + l;
        const float bias = bq[n0 + col];
#pragma unroll
        for (int mt = 0; mt < 4; ++mt)
#pragma unroll
          for (int rg = 0; rg < 4; ++rg)
            T[(mt * 16 + ql * 4 + rg) * 136 + col] = f2b(acc[mt][nt][rg] + bias);
      }
    }
    __syncthreads();
    if (which < 2) {
      u16* const dst = which ? Kh : Qh;
#pragma unroll
      for (int h = 0; h < 2; ++h) {
        const size_t bnoff = ((size_t)(bb * 16 + h0 + h)) << 16;
#pragma unroll
        for (int it = 0; it < 2; ++it) {
          const int c = it * 256 + t;
          const int r = c >> 3, d8 = (c & 7) * 8;
          const uint4 v = *(const uint4*)(T + r * 136 + h * 64 + d8);
          *(uint4*)(dst + bnoff + ((size_t)(qbase + pass * 64 + r) << 6) + d8) = v;
        }
      }
    } else {
#pragma unroll
      for (int h = 0; h < 2; ++h) {
        const size_t bnoff = ((size_t)(bb * 16 + h0 + h)) << 16;
#pragma unroll
        for (int it = 0; it < 2; ++it) {
          const int c = it * 256 + t;
          const int dr = c >> 3, q8 = (c & 7) * 8;
          u32 pk[4];
#pragma unroll
          for (int e = 0; e < 4; ++e) {
            const u16 lo = T[(q8 + 2 * e + 0) * 136 + h * 64 + dr];
            const u16 hi = T[(q8 + 2 * e + 1) * 136 + h * 64 + dr];
            pk[e] = (u32)lo | ((u32)hi << 16);
          }
          *(uint4*)(Vt + bnoff + ((size_t)dr << 10) + qbase + pass * 64 + q8) =
              make_uint4(pk[0], pk[1], pk[2], pk[3]);
        }
      }
    }
  }
}

// ---------------------------------------------------------------------------
// rel_attn: round-1 structure (P ring in LDS, 1 barrier/iter) + K/V fragments
// moved OUT of the LDS pipe: loaded global->VGPR with prefetch distance and
// counted vmcnt waits (T3/T4). V[k] issued at iter top (used in PV ~3Kcy
// later); K[k+1] issued after z1 consumes K[k] (used next iter). P-DMA for
// iter k+1 drained via asm vmcnt(18) + raw s_barrier so K/V prefetches stay
// in flight ACROSS the barrier (never vmcnt(0)).
// vmcnt ledger (steady state, per wave, oldest->newest):
//   top of iter: {PDMA[k](2), K[k](8)}            = 10
//   +V[k](8) +PDMA[k+1](2)                        = 20
//   vmcnt(18) retires PDMA[k]; barrier            -> P[k] resident all waves
//   z1 auto-wait vmcnt(10) retires K[k]; +K[k+1](8)
//   PV auto-wait vmcnt(10) retires V[k]           -> invariant restored
// LDS = ring 32KB + prob 8KB = 40KB. Removes 16 of 32 ds_read_b128/wave-iter
// + all K/V DMA (LDS pipe was ~75% busy in round 1 -> the wall).
// ---------------------------------------------------------------------------
__global__ __launch_bounds__(256, 2) void rel_attn(
    const u16* __restrict__ Qh, const u16* __restrict__ Kh,
    const u16* __restrict__ Vt, const u16* __restrict__ Pb,
    const float* __restrict__ rrb, const float* __restrict__ rwb,
    float* __restrict__ out)
{
  __shared__ u16 smem[20480];        // 40960 B
  u16* const sPr   = smem;           // [256][64] P ring, 64-row quadrants
  u16* const sProb = smem + 16384;   // [128][32] swizzled half-tile

  const int t = threadIdx.x;
  const int lane = t & 63, w = t >> 6;
  const int l = lane & 15, ql = lane >> 4;
  const int vid = blockIdx.x;
  const int qt = vid >> 6, bn = vid & 63;          // vid&7 == bn&7 (XCD)
  const int n = bn & 15, bb = bn >> 4;
  const size_t hoff = (size_t)bn << 16;
  const int q0 = qt << 7;
  const int bz = 6 - 2 * w;                        // z2 rel-tile base

  // A-frags in registers: U = Q + rr, W = Q + rw + K (round-2 construction)
  bf16x8 au[2][2], aw[2][2];                       // [mt][ks]
#pragma unroll
  for (int mt = 0; mt < 2; ++mt)
#pragma unroll
    for (int ks = 0; ks < 2; ++ks) {
      const int row = w * 32 + mt * 16 + l;
      const int d = ks * 32 + ql * 8;
      const uint4 qv = *(const uint4*)(Qh + hoff + ((size_t)(q0 + row) << 6) + d);
      const uint4 kv = *(const uint4*)(Kh + hoff + ((size_t)(q0 + row) << 6) + d);
      float rv[8], wv[8];
      *(float4*)&rv[0] = *(const float4*)(rrb + n * 64 + d);
      *(float4*)&rv[4] = *(const float4*)(rrb + n * 64 + d + 4);
      *(float4*)&wv[0] = *(const float4*)(rwb + n * 64 + d);
      *(float4*)&wv[4] = *(const float4*)(rwb + n * 64 + d + 4);
      const u16* qp = (const u16*)&qv;
      const u16* kp = (const u16*)&kv;
      u16 uo[8], wo[8];
#pragma unroll
      for (int e = 0; e < 8; ++e) {
        const float qf = b2f(qp[e]);
        uo[e] = f2b(qf + rv[e]);
        wo[e] = f2b(qf + wv[e] + b2f(kp[e]));
      }
      au[mt][ks] = *(const bf16x8*)uo;
      aw[mt][ks] = *(const bf16x8*)wo;
    }

  // prologue: P band rows [lbase0, lbase0+192) via DMA, then K[0] frags
  {
    const int lbase0 = 897 - q0;
    const int rb0 = (896 - q0) & 255;
#pragma unroll
    for (int j = 0; j < 6; ++j) {
      const int ii = w * 6 + j;
      const int m = ii * 8 + (lane >> 3);
      const int q8 = (lane & 7) ^ (m & 7);
      __builtin_amdgcn_global_load_lds(
          (const AS1 u32*)(Pb + ((size_t)(lbase0 + m) << 6) + q8 * 8),
          (AS3 u32*)(sPr + ((rb0 + ii * 8) & 255) * 64), 16, 0, 0);
    }
  }
  __builtin_amdgcn_sched_barrier(0);
  bf16x8 kf[8];                      // K[k] frags, single buffer (reload late)
#pragma unroll
  for (int ks = 0; ks < 2; ++ks)
#pragma unroll
    for (int nt = 0; nt < 4; ++nt)
      kf[ks * 4 + nt] = *(const bf16x8*)(
          Kh + hoff + ((size_t)(nt * 16 + l) << 6) + ks * 32 + ql * 8);
  __builtin_amdgcn_sched_barrier(0);

  const f32x4 Z0 = (f32x4){0.f, 0.f, 0.f, 0.f};
  f32x4 o[2][4];
  float lrun[2][4];
#pragma unroll
  for (int mt = 0; mt < 2; ++mt)
#pragma unroll
    for (int ii = 0; ii < 4; ++ii) {
      o[mt][ii] = (f32x4){0.f, 0.f, 0.f, 0.f};
      lrun[mt][ii] = 0.f;
    }

  for (int k0 = 0; k0 < 1024; k0 += 64) {
    const int rb = (896 + k0 - q0) & 255;     // ring quadrant base

    // V[k] frags -> regs (used in PV at iter end; latency hidden)
    bf16x8 vf[8];
#pragma unroll
    for (int ks = 0; ks < 2; ++ks)
#pragma unroll
      for (int dt = 0; dt < 4; ++dt)
        vf[ks * 4 + dt] = *(const bf16x8*)(
            Vt + hoff + ((size_t)(dt * 16 + l) << 10) + k0 + ks * 32 + ql * 8);
    __builtin_amdgcn_sched_barrier(0);

    // P-DMA for iter k+1: new rows [lbase+192, lbase+256) -> ring (rb+192)
    {
      const int lb2 = 897 + k0 - q0 + 192;
#pragma unroll
      for (int j = 0; j < 2; ++j) {
        const int ii = w * 2 + j;
        const int m = ii * 8 + (lane >> 3);
        const int q8 = (lane & 7) ^ (m & 7);
        const int grow = min(lb2 + m, 2048);  // clamp last-iter overrun
        __builtin_amdgcn_global_load_lds(
            (const AS1 u32*)(Pb + ((size_t)grow << 6) + q8 * 8),
            (AS3 u32*)(sPr + ((rb + 192 + ii * 8) & 255) * 64), 16, 0, 0);
      }
    }
    __builtin_amdgcn_sched_barrier(0);
    asm volatile("s_waitcnt vmcnt(18)" ::: "memory");  // drain own P-DMA[k]
    __builtin_amdgcn_s_barrier();                      // all waves' P[k] in
    __builtin_amdgcn_sched_barrier(0);

    // z1 = U.K^T (K frags from regs), z2 = W.Pband^T (ring)
    f32x4 z1[2][4], z2[2][5];
    __builtin_amdgcn_s_setprio(1);
#pragma unroll
    for (int ks = 0; ks < 2; ++ks) {
#pragma unroll
      for (int nt = 0; nt < 4; ++nt) {
        const bf16x8 bk = kf[ks * 4 + nt];
#pragma unroll
        for (int mt = 0; mt < 2; ++mt)
          z1[mt][nt] = __builtin_amdgcn_mfma_f32_16x16x32_bf16(
              au[mt][ks], bk, ks ? z1[mt][nt] : Z0, 0, 0, 0);
      }
      // 6 shared P B-tiles; mt=0 uses rel tiles 1..5, mt=1 uses 0..4
#pragma unroll
      for (int rt = 0; rt < 6; ++rt) {
        const int row = (bz + rt) * 16 + l;
        const bf16x8 bp = *(const bf16x8*)(
            sPr + ((rb + row) & 255) * 64 + (((ks * 4 + ql) ^ (row & 7)) * 8));
        if (rt >= 1)
          z2[0][rt - 1] = __builtin_amdgcn_mfma_f32_16x16x32_bf16(
              aw[0][ks], bp, ks ? z2[0][rt - 1] : Z0, 0, 0, 0);
        if (rt <= 4)
          z2[1][rt] = __builtin_amdgcn_mfma_f32_16x16x32_bf16(
              aw[1][ks], bp, ks ? z2[1][rt] : Z0, 0, 0, 0);
      }
    }
    __builtin_amdgcn_s_setprio(0);

    // K[k+1] reload into kf (after last kf use; cover = gather + PV)
    {
      const int kn = (k0 + 64) & 1023;       // wraps on last iter (discarded)
#pragma unroll
      for (int ks = 0; ks < 2; ++ks)
#pragma unroll
        for (int nt = 0; nt < 4; ++nt)
          kf[ks * 4 + nt] = *(const bf16x8*)(
              Kh + hoff + ((size_t)(kn + nt * 16 + l) << 6) + ks * 32 + ql * 8);
    }
    __builtin_amdgcn_sched_barrier(0);

    // diagonal gather + exp2 (rows i = 32w + 16mt + 4ql + ii)
    float p[2][4][4];
#pragma unroll
    for (int mt = 0; mt < 2; ++mt)
#pragma unroll
      for (int ii = 0; ii < 4; ++ii) {
        const int ci = 15 - ql * 4 - ii;               // c' & 15
        const int src = (lane & 48) | ((l + ci) & 15);
        const bool wrap = l < ci;
#pragma unroll
        for (int jt = 0; jt < 4; ++jt) {
          const float val = wrap ? z2[mt][jt + 1][ii] : z2[mt][jt][ii];
          const float g = __shfl(val, src, 64);
          const float pv =
              __builtin_amdgcn_exp2f((z1[mt][jt][ii] + g) * 0.18033688011112042f);
          p[mt][ii][jt] = pv;
          lrun[mt][ii] += pv;
        }
      }

    // PV in two K=32 steps through the half-tile wave-private prob buffer
#pragma unroll
    for (int ks = 0; ks < 2; ++ks) {
#pragma unroll
      for (int mt = 0; mt < 2; ++mt)
#pragma unroll
        for (int ii = 0; ii < 4; ++ii) {
          const int r = w * 32 + mt * 16 + ql * 4 + ii;
          const int sw2 = (r & 3) ^ ((r >> 2) & 3);
#pragma unroll
          for (int jh = 0; jh < 2; ++jh) {
            const int ch = jh * 2 + (l >> 3);
            sProb[r * 32 + ((ch ^ sw2) * 8) + (l & 7)] =
                f2b_fast(p[mt][ii][ks * 2 + jh]);
          }
        }
      __builtin_amdgcn_s_setprio(1);
#pragma unroll
      for (int mt = 0; mt < 2; ++mt) {
        const int ar = w * 32 + mt * 16 + l;
        const bf16x8 ap = *(const bf16x8*)(
            sProb + ar * 32 + ((ql ^ ((ar & 3) ^ ((ar >> 2) & 3))) * 8));
#pragma unroll
        for (int dt = 0; dt < 4; ++dt)
          o[mt][dt] = __builtin_amdgcn_mfma_f32_16x16x32_bf16(
              ap, vf[ks * 4 + dt], o[mt][dt], 0, 0, 0);
      }
      __builtin_amdgcn_s_setprio(0);
    }
  }

  // epilogue: row-sum reduce, normalize, store fp32 (B, L, D)
#pragma unroll
  for (int mt = 0; mt < 2; ++mt)
#pragma unroll
    for (int ii = 0; ii < 4; ++ii) {
      float ls = lrun[mt][ii];
      ls += __shfl_xor(ls, 1);
      ls += __shfl_xor(ls, 2);
      ls += __shfl_xor(ls, 4);
      ls += __shfl_xor(ls, 8);
      const float inv = 1.f / ls;
      const int q = q0 + w * 32 + mt * 16 + ql * 4 + ii;
#pragma unroll
      for (int dt = 0; dt < 4; ++dt)
        out[((size_t)(bb * 1024 + q) << 10) + (n << 6) + dt * 16 + l] =
            o[mt][dt][ii] * inv;
    }
}

// ---------------------------------------------------------------------------
extern "C" void kernel_launch(void* const* d_in, const int* in_sizes, int n_in,
                              void* d_out, int out_size, void* d_ws, size_t ws_size,
                              hipStream_t stream) {
  const float* x  = (const float*)d_in[0];  // (4,1024,1024)
  const float* P  = (const float*)d_in[1];  // (2048,64)
  const float* Wq = (const float*)d_in[2];  // (1024,3072)
  const float* bq = (const float*)d_in[3];  // (3072,)
  const float* rr = (const float*)d_in[4];  // (16,64)
  const float* rw = (const float*)d_in[5];  // (16,64)
  float* out = (float*)d_out;

  char* ws = (char*)d_ws;
  u16* xb = (u16*)(ws);                      // 8 MB
  u16* Wt = (u16*)(ws + 8388608);            // 6 MB  [3072][1024]
  u16* Pb = (u16*)(ws + 14680064);           // 2049 rows x 64 (+guard)
  u16* Qh = (u16*)(ws + 14946304);           // 8 MB  [bn][q][d]
  u16* Kh = (u16*)(ws + 23334912);           // 8 MB
  u16* Vt = (u16*)(ws + 31723520);           // 8 MB  [bn][d][q]

  prep<<<4993, 256, 0, stream>>>(x, Wq, P, xb, Wt, Pb);
  qkv_gemm<<<768, 256, 0, stream>>>(xb, Wt, bq, Qh, Kh, Vt);
  rel_attn<<<512, 256, 0, stream>>>(Qh, Kh, Vt, Pb, rr, rw, out);
}

// Round 4
// 172.092 us; speedup vs baseline: 1.3398x; 1.0738x over previous
//
#include <hip/hip_runtime.h>
#include <math.h>

typedef unsigned short u16;
typedef unsigned int u32;
typedef __attribute__((ext_vector_type(8))) short bf16x8;
typedef __attribute__((ext_vector_type(4))) float f32x4;

#define AS1 __attribute__((address_space(1)))
#define AS3 __attribute__((address_space(3)))

static __device__ __forceinline__ u16 f2b(float f) {
  u32 u = __float_as_uint(f);
  return (u16)((u + 0x7FFFu + ((u >> 16) & 1u)) >> 16);
}
static __device__ __forceinline__ u16 f2b_fast(float f) {   // round-half-up
  return (u16)((__float_as_uint(f) + 0x8000u) >> 16);
}
static __device__ __forceinline__ float b2f(u16 b) {
  return __uint_as_float(((u32)b) << 16);
}

// ---------------------------------------------------------------------------
// prep: cast x (4096x1024) -> bf16; P (2048x64) -> bf16 (+ guard row 2048);
//       W (1024x3072) -> Wt bf16 TRANSPOSED [3072][1024] via LDS tiles.
// ---------------------------------------------------------------------------
__global__ __launch_bounds__(256) void prep(
    const float* __restrict__ x, const float* __restrict__ W,
    const float* __restrict__ P,
    u16* __restrict__ xb, u16* __restrict__ Wt, u16* __restrict__ Pb)
{
  __shared__ u16 sT[64 * 68];
  const int bid = blockIdx.x, t = threadIdx.x;
  if (bid < 4096) {
    const size_t base = (size_t)bid * 1024 + t * 4;
    const float4 v = *(const float4*)(x + base);
    const u32 lo = (u32)f2b(v.x) | ((u32)f2b(v.y) << 16);
    const u32 hi = (u32)f2b(v.z) | ((u32)f2b(v.w) << 16);
    *(uint2*)(xb + base) = make_uint2(lo, hi);
  } else if (bid < 4224) {
    const size_t base = (size_t)(bid - 4096) * 1024 + t * 4;
    const float4 v = *(const float4*)(P + base);
    const u32 lo = (u32)f2b(v.x) | ((u32)f2b(v.y) << 16);
    const u32 hi = (u32)f2b(v.z) | ((u32)f2b(v.w) << 16);
    *(uint2*)(Pb + base) = make_uint2(lo, hi);
  } else if (bid < 4992) {
    const int tb = bid - 4224;
    const int tk = tb / 48, tn = tb % 48;
    const int k0 = tk * 64, n0 = tn * 64;
#pragma unroll
    for (int it = 0; it < 4; ++it) {
      const int c = it * 256 + t;
      const int r = c >> 4, c4 = (c & 15) << 2;
      const float4 v = *(const float4*)(W + (size_t)(k0 + r) * 3072 + n0 + c4);
      sT[(c4 + 0) * 68 + r] = f2b(v.x);
      sT[(c4 + 1) * 68 + r] = f2b(v.y);
      sT[(c4 + 2) * 68 + r] = f2b(v.z);
      sT[(c4 + 3) * 68 + r] = f2b(v.w);
    }
    __syncthreads();
#pragma unroll
    for (int it = 0; it < 4; ++it) {
      const int c = it * 256 + t;
      const int rr = c >> 4, k4 = (c & 15) << 2;
      const uint2 rv = *(const uint2*)(sT + rr * 68 + k4);
      *(uint2*)(Wt + (size_t)(n0 + rr) * 1024 + k0 + k4) = rv;
    }
  } else {
    if (t < 64) Pb[2048 * 64 + t] = f2b(P[2047 * 64 + t]);  // guard row
  }
}

// ---------------------------------------------------------------------------
// qkv_gemm (bf16 MFMA): C = xb(4096x1024) @ Wt^T(1024x3072) + bias.
// 128x128 tile, BK=64, XOR-swizzled LDS, global_load_lds 16B, XCD-aware grid.
// Epilogue: LDS repack -> coalesced stores.
// THIS ROUND: V blocks store the repack tile TRANSPOSED in LDS (Tv[col][row],
// pitch 72 u16 so rows are 16B-aligned): writer packs 4 consecutive rows into
// one uint2 (16 stores vs 64 b16), reader becomes 4 aligned uint4 LDS reads
// (vs 64 scalar ds_read_u16) feeding the coalesced Vt stores.
// ---------------------------------------------------------------------------
__global__ __launch_bounds__(256, 3) void qkv_gemm(
    const u16* __restrict__ xb, const u16* __restrict__ Wt,
    const float* __restrict__ bq,
    u16* __restrict__ Qh, u16* __restrict__ Kh, u16* __restrict__ Vt)
{
  __shared__ u16 smem[16384];        // 32 KB: sA | sB, reused as repack tile
  u16* const sA = smem;
  u16* const sB = smem + 8192;
  u16* const T  = smem;              // epilogue tile [64][136] (Q/K)
  u16* const Tv = smem;              // epilogue tile [128][72] (V, transposed)
  const int t = threadIdx.x;
  const int lane = t & 63, w = t >> 6;
  const int l = lane & 15, ql = lane >> 4;
  const int wm = w & 1, wn = w >> 1;
  const int vid = blockIdx.x;
  const int xcd = vid & 7, jj = vid >> 3;          // jj in [0,96)
  const int n0 = (xcd * 3 + (jj % 3)) * 128;
  const int m0 = (jj / 3) * 128;

  f32x4 acc[4][4];
#pragma unroll
  for (int i = 0; i < 4; ++i)
#pragma unroll
    for (int j = 0; j < 4; ++j) acc[i][j] = (f32x4){0.f, 0.f, 0.f, 0.f};

  for (int k0 = 0; k0 < 1024; k0 += 64) {
    __syncthreads();
#pragma unroll
    for (int j = 0; j < 4; ++j) {
      const int ii = w * 4 + j;
      const int m = ii * 8 + (lane >> 3);
      const int q8 = (lane & 7) ^ (m & 7);
      __builtin_amdgcn_global_load_lds(
          (const AS1 u32*)(xb + (size_t)(m0 + m) * 1024 + k0 + q8 * 8),
          (AS3 u32*)(sA + ii * 512), 16, 0, 0);
      __builtin_amdgcn_global_load_lds(
          (const AS1 u32*)(Wt + (size_t)(n0 + m) * 1024 + k0 + q8 * 8),
          (AS3 u32*)(sB + ii * 512), 16, 0, 0);
    }
    __syncthreads();
#pragma unroll
    for (int ks = 0; ks < 2; ++ks) {
      bf16x8 a[4], b[4];
#pragma unroll
      for (int mt = 0; mt < 4; ++mt) {
        const int m = wm * 64 + mt * 16 + l;
        a[mt] = *(const bf16x8*)(sA + m * 64 + (((ks * 4 + ql) ^ (m & 7)) * 8));
      }
#pragma unroll
      for (int nt = 0; nt < 4; ++nt) {
        const int nn = wn * 64 + nt * 16 + l;
        b[nt] = *(const bf16x8*)(sB + nn * 64 + (((ks * 4 + ql) ^ (nn & 7)) * 8));
      }
#pragma unroll
      for (int mt = 0; mt < 4; ++mt)
#pragma unroll
        for (int nt = 0; nt < 4; ++nt)
          acc[mt][nt] = __builtin_amdgcn_mfma_f32_16x16x32_bf16(
              a[mt], b[nt], acc[mt][nt], 0, 0, 0);
    }
  }

  const int which = n0 >> 10;                 // 0=Q 1=K 2=V (uniform per block)
  const int qbase = m0 & 1023;
  const int bb = m0 >> 10;
  const int h0 = (n0 & 1023) >> 6;
#pragma unroll
  for (int pass = 0; pass < 2; ++pass) {
    __syncthreads();
    if (which < 2) {
      if (wm == pass) {
#pragma unroll
        for (int nt = 0; nt < 4; ++nt) {
          const int col = wn * 64 + nt * 16 + l;
          const float bias = bq[n0 + col];
#pragma unroll
          for (int mt = 0; mt < 4; ++mt)
#pragma unroll
            for (int rg = 0; rg < 4; ++rg)
              T[(mt * 16 + ql * 4 + rg) * 136 + col] = f2b(acc[mt][nt][rg] + bias);
        }
      }
      __syncthreads();
      u16* const dst = which ? Kh : Qh;
#pragma unroll
      for (int h = 0; h < 2; ++h) {
        const size_t bnoff = ((size_t)(bb * 16 + h0 + h)) << 16;
#pragma unroll
        for (int it = 0; it < 2; ++it) {
          const int c = it * 256 + t;
          const int r = c >> 3, d8 = (c & 7) * 8;
          const uint4 v = *(const uint4*)(T + r * 136 + h * 64 + d8);
          *(uint4*)(dst + bnoff + ((size_t)(qbase + pass * 64 + r) << 6) + d8) = v;
        }
      }
    } else {
      // V: transposed repack tile Tv[col=128][row=64], pitch 72 (16B-aligned)
      if (wm == pass) {
#pragma unroll
        for (int nt = 0; nt < 4; ++nt) {
          const int col = wn * 64 + nt * 16 + l;
          const float bias = bq[n0 + col];
#pragma unroll
          for (int mt = 0; mt < 4; ++mt) {
            const u32 lo = (u32)f2b(acc[mt][nt][0] + bias) |
                           ((u32)f2b(acc[mt][nt][1] + bias) << 16);
            const u32 hi = (u32)f2b(acc[mt][nt][2] + bias) |
                           ((u32)f2b(acc[mt][nt][3] + bias) << 16);
            *(uint2*)(Tv + col * 72 + mt * 16 + ql * 4) = make_uint2(lo, hi);
          }
        }
      }
      __syncthreads();
#pragma unroll
      for (int h = 0; h < 2; ++h) {
        const size_t bnoff = ((size_t)(bb * 16 + h0 + h)) << 16;
#pragma unroll
        for (int it = 0; it < 2; ++it) {
          const int c = it * 256 + t;
          const int dr = c >> 3, q8 = (c & 7) * 8;
          const uint4 v = *(const uint4*)(Tv + (h * 64 + dr) * 72 + q8);
          *(uint4*)(Vt + bnoff + ((size_t)dr << 10) + qbase + pass * 64 + q8) = v;
        }
      }
    }
  }
}

// ---------------------------------------------------------------------------
// rel_attn (bf16 MFMA flash, no-max softmax): 128-row q-tile per block.
// Round-1 verified structure (59.5us): K/V double-buffered LDS via DMA, P in
// a 256-row ring (64 new rows staged/iter), prefetch for iter k+1 issued
// right after the single per-iter barrier, z1/z2 MFMA-zero-init, setprio
// around MFMA clusters. LDS 72KB -> 2 blocks/CU (grid-capped anyway).
// ---------------------------------------------------------------------------
__global__ __launch_bounds__(256, 2) void rel_attn(
    const u16* __restrict__ Qh, const u16* __restrict__ Kh,
    const u16* __restrict__ Vt, const u16* __restrict__ Pb,
    const float* __restrict__ rrb, const float* __restrict__ rwb,
    float* __restrict__ out)
{
  __shared__ u16 smem[36864];        // 73728 B
  u16* const sK    = smem;           // [2][64][64] swizzled, double-buffered
  u16* const sVT   = smem + 8192;    // [2][64][64] swizzled (rows=d, cols=j)
  u16* const sPr   = smem + 16384;   // [256][64]   P ring, 64-row quadrants
  u16* const sProb = smem + 32768;   // [128][32]   swizzled half-tile
  u16* const sU    = smem;           // transient alias [128][64]
  u16* const sW    = smem + 16384;   // transient alias [128][64]

  const int t = threadIdx.x;
  const int lane = t & 63, w = t >> 6;
  const int l = lane & 15, ql = lane >> 4;
  const int vid = blockIdx.x;
  const int qt = vid >> 6, bn = vid & 63;          // vid&7 == bn&7 (XCD)
  const int n = bn & 15, bb = bn >> 4;
  const size_t hoff = (size_t)bn << 16;
  const int q0 = qt << 7;
  const int bz = 6 - 2 * w;                        // z2 rel-tile base

  // stage U = Q+rr, W = Q+rw+K (128 query rows), swizzled pitch-64
#pragma unroll
  for (int it = 0; it < 4; ++it) {
    const int c = it * 256 + t;
    const int i = c >> 3, ch = c & 7;
    const int d8 = ch * 8;
    const uint4 qv = *(const uint4*)(Qh + hoff + ((size_t)(q0 + i) << 6) + d8);
    const uint4 kv = *(const uint4*)(Kh + hoff + ((size_t)(q0 + i) << 6) + d8);
    const u16* qp = (const u16*)&qv;
    const u16* kp = (const u16*)&kv;
    u16 uo[8], wo[8];
#pragma unroll
    for (int e = 0; e < 8; ++e) {
      const float rv = rrb[n * 64 + d8 + e];
      const float wv = rwb[n * 64 + d8 + e];
      const float qf = b2f(qp[e]), kf = b2f(kp[e]);
      uo[e] = f2b(qf + rv);
      wo[e] = f2b(qf + wv + kf);
    }
    const int pos = i * 64 + ((ch ^ (i & 7)) * 8);
    *(uint4*)(sU + pos) = *(const uint4*)uo;
    *(uint4*)(sW + pos) = *(const uint4*)wo;
  }
  __syncthreads();

  bf16x8 au[2][2], aw[2][2];         // [mt][ks], loop-invariant A-frags
#pragma unroll
  for (int mt = 0; mt < 2; ++mt)
#pragma unroll
    for (int ks = 0; ks < 2; ++ks) {
      const int row = w * 32 + mt * 16 + l;
      const int off = row * 64 + (((ks * 4 + ql) ^ (row & 7)) * 8);
      au[mt][ks] = *(const bf16x8*)(sU + off);
      aw[mt][ks] = *(const bf16x8*)(sW + off);
    }
  __syncthreads();   // all frag reads done before DMA overwrites sU/sW region

  // initial staging: K(0)->sK[0], V(0)->sVT[0], P rows [lbase0, lbase0+192)
  {
#pragma unroll
    for (int j = 0; j < 2; ++j) {
      const int ii = w * 2 + j;
      const int m = ii * 8 + (lane >> 3);
      const int q8 = (lane & 7) ^ (m & 7);
      __builtin_amdgcn_global_load_lds(
          (const AS1 u32*)(Kh + hoff + ((size_t)m << 6) + q8 * 8),
          (AS3 u32*)(sK + ii * 512), 16, 0, 0);
      __builtin_amdgcn_global_load_lds(
          (const AS1 u32*)(Vt + hoff + ((size_t)m << 10) + q8 * 8),
          (AS3 u32*)(sVT + ii * 512), 16, 0, 0);
    }
    const int lbase0 = 897 - q0;
    const int rb0 = (896 - q0) & 255;
#pragma unroll
    for (int j = 0; j < 6; ++j) {
      const int ii = w * 6 + j;
      const int m = ii * 8 + (lane >> 3);
      const int q8 = (lane & 7) ^ (m & 7);
      __builtin_amdgcn_global_load_lds(
          (const AS1 u32*)(Pb + ((size_t)(lbase0 + m) << 6) + q8 * 8),
          (AS3 u32*)(sPr + ((rb0 + ii * 8) & 255) * 64), 16, 0, 0);
    }
  }

  const f32x4 Z0 = (f32x4){0.f, 0.f, 0.f, 0.f};
  f32x4 o[2][4];
  float lrun[2][4];
#pragma unroll
  for (int mt = 0; mt < 2; ++mt)
#pragma unroll
    for (int ii = 0; ii < 4; ++ii) {
      o[mt][ii] = (f32x4){0.f, 0.f, 0.f, 0.f};
      lrun[mt][ii] = 0.f;
    }

  for (int k0 = 0; k0 < 1024; k0 += 64) {
    const int cb = (k0 >> 6) & 1;
    const int rb = (896 + k0 - q0) & 255;     // ring quadrant base (lbase-1)
    __syncthreads();   // drains own vmcnt -> this iter's tiles are resident

    if (k0 < 960) {    // prefetch iter k+1: 6 loads/wave, issued pre-compute
      const int kn = k0 + 64;
#pragma unroll
      for (int j = 0; j < 2; ++j) {
        const int ii = w * 2 + j;
        const int m = ii * 8 + (lane >> 3);
        const int q8 = (lane & 7) ^ (m & 7);
        __builtin_amdgcn_global_load_lds(
            (const AS1 u32*)(Kh + hoff + ((size_t)(kn + m) << 6) + q8 * 8),
            (AS3 u32*)(sK + (cb ^ 1) * 4096 + ii * 512), 16, 0, 0);
        __builtin_amdgcn_global_load_lds(
            (const AS1 u32*)(Vt + hoff + ((size_t)m << 10) + kn + q8 * 8),
            (AS3 u32*)(sVT + (cb ^ 1) * 4096 + ii * 512), 16, 0, 0);
        // new P rows [lbase+192, lbase+256) -> ring quadrant (rb+192)
        __builtin_amdgcn_global_load_lds(
            (const AS1 u32*)(Pb + ((size_t)(897 + kn + 128 - q0 + m) << 6) + q8 * 8),
            (AS3 u32*)(sPr + ((rb + 192 + ii * 8) & 255) * 64), 16, 0, 0);
      }
    }

    const u16* const cK = sK + cb * 4096;
    const u16* const cV = sVT + cb * 4096;

    f32x4 z1[2][4], z2[2][5];
    __builtin_amdgcn_s_setprio(1);
#pragma unroll
    for (int ks = 0; ks < 2; ++ks) {
#pragma unroll
      for (int nt = 0; nt < 4; ++nt) {
        const int row = nt * 16 + l;
        const bf16x8 bk =
            *(const bf16x8*)(cK + row * 64 + (((ks * 4 + ql) ^ (row & 7)) * 8));
#pragma unroll
        for (int mt = 0; mt < 2; ++mt)
          z1[mt][nt] = __builtin_amdgcn_mfma_f32_16x16x32_bf16(
              au[mt][ks], bk, ks ? z1[mt][nt] : Z0, 0, 0, 0);
      }
      // 6 shared P B-tiles from the ring; mt=0 uses rel 1..5, mt=1 uses 0..4
#pragma unroll
      for (int rt = 0; rt < 6; ++rt) {
        const int row = (bz + rt) * 16 + l;
        const bf16x8 bp = *(const bf16x8*)(
            sPr + ((rb + row) & 255) * 64 + (((ks * 4 + ql) ^ (row & 7)) * 8));
        if (rt >= 1)
          z2[0][rt - 1] = __builtin_amdgcn_mfma_f32_16x16x32_bf16(
              aw[0][ks], bp, ks ? z2[0][rt - 1] : Z0, 0, 0, 0);
        if (rt <= 4)
          z2[1][rt] = __builtin_amdgcn_mfma_f32_16x16x32_bf16(
              aw[1][ks], bp, ks ? z2[1][rt] : Z0, 0, 0, 0);
      }
    }
    __builtin_amdgcn_s_setprio(0);

    // diagonal gather + exp2 (rows i = 32w + 16mt + 4ql + ii)
    float p[2][4][4];
#pragma unroll
    for (int mt = 0; mt < 2; ++mt)
#pragma unroll
      for (int ii = 0; ii < 4; ++ii) {
        const int ci = 15 - ql * 4 - ii;               // c' & 15
        const int src = (lane & 48) | ((l + ci) & 15);
        const bool wrap = l < ci;
#pragma unroll
        for (int jt = 0; jt < 4; ++jt) {
          const float val = wrap ? z2[mt][jt + 1][ii] : z2[mt][jt][ii];
          const float g = __shfl(val, src, 64);
          const float pv =
              __builtin_amdgcn_exp2f((z1[mt][jt][ii] + g) * 0.18033688011112042f);
          p[mt][ii][jt] = pv;
          lrun[mt][ii] += pv;
        }
      }

    // PV in two K=32 steps through the half-tile wave-private prob buffer
#pragma unroll
    for (int ks = 0; ks < 2; ++ks) {
#pragma unroll
      for (int mt = 0; mt < 2; ++mt)
#pragma unroll
        for (int ii = 0; ii < 4; ++ii) {
          const int r = w * 32 + mt * 16 + ql * 4 + ii;
          const int sw2 = (r & 3) ^ ((r >> 2) & 3);
#pragma unroll
          for (int jh = 0; jh < 2; ++jh) {
            const int ch = jh * 2 + (l >> 3);
            sProb[r * 32 + ((ch ^ sw2) * 8) + (l & 7)] =
                f2b_fast(p[mt][ii][ks * 2 + jh]);
          }
        }
      bf16x8 bv[4];
#pragma unroll
      for (int dt = 0; dt < 4; ++dt) {
        const int row = dt * 16 + l;
        bv[dt] =
            *(const bf16x8*)(cV + row * 64 + (((ks * 4 + ql) ^ (row & 7)) * 8));
      }
      __builtin_amdgcn_s_setprio(1);
#pragma unroll
      for (int mt = 0; mt < 2; ++mt) {
        const int ar = w * 32 + mt * 16 + l;
        const bf16x8 ap = *(const bf16x8*)(
            sProb + ar * 32 + ((ql ^ ((ar & 3) ^ ((ar >> 2) & 3))) * 8));
#pragma unroll
        for (int dt = 0; dt < 4; ++dt)
          o[mt][dt] = __builtin_amdgcn_mfma_f32_16x16x32_bf16(
              ap, bv[dt], o[mt][dt], 0, 0, 0);
      }
      __builtin_amdgcn_s_setprio(0);
    }
  }

  // epilogue: row-sum reduce, normalize, store fp32 (B, L, D)
#pragma unroll
  for (int mt = 0; mt < 2; ++mt)
#pragma unroll
    for (int ii = 0; ii < 4; ++ii) {
      float ls = lrun[mt][ii];
      ls += __shfl_xor(ls, 1);
      ls += __shfl_xor(ls, 2);
      ls += __shfl_xor(ls, 4);
      ls += __shfl_xor(ls, 8);
      const float inv = 1.f / ls;
      const int q = q0 + w * 32 + mt * 16 + ql * 4 + ii;
#pragma unroll
      for (int dt = 0; dt < 4; ++dt)
        out[((size_t)(bb * 1024 + q) << 10) + (n << 6) + dt * 16 + l] =
            o[mt][dt][ii] * inv;
    }
}

// ---------------------------------------------------------------------------
extern "C" void kernel_launch(void* const* d_in, const int* in_sizes, int n_in,
                              void* d_out, int out_size, void* d_ws, size_t ws_size,
                              hipStream_t stream) {
  const float* x  = (const float*)d_in[0];  // (4,1024,1024)
  const float* P  = (const float*)d_in[1];  // (2048,64)
  const float* Wq = (const float*)d_in[2];  // (1024,3072)
  const float* bq = (const float*)d_in[3];  // (3072,)
  const float* rr = (const float*)d_in[4];  // (16,64)
  const float* rw = (const float*)d_in[5];  // (16,64)
  float* out = (float*)d_out;

  char* ws = (char*)d_ws;
  u16* xb = (u16*)(ws);                      // 8 MB
  u16* Wt = (u16*)(ws + 8388608);            // 6 MB  [3072][1024]
  u16* Pb = (u16*)(ws + 14680064);           // 2049 rows x 64 (+guard)
  u16* Qh = (u16*)(ws + 14946304);           // 8 MB  [bn][q][d]
  u16* Kh = (u16*)(ws + 23334912);           // 8 MB
  u16* Vt = (u16*)(ws + 31723520);           // 8 MB  [bn][d][q]

  prep<<<4993, 256, 0, stream>>>(x, Wq, P, xb, Wt, Pb);
  qkv_gemm<<<768, 256, 0, stream>>>(xb, Wt, bq, Qh, Kh, Vt);
  rel_attn<<<512, 256, 0, stream>>>(Qh, Kh, Vt, Pb, rr, rw, out);
}

// Round 5
// 163.458 us; speedup vs baseline: 1.4105x; 1.0528x over previous
//
#include <hip/hip_runtime.h>
#include <math.h>

typedef unsigned short u16;
typedef unsigned int u32;
typedef __attribute__((ext_vector_type(8))) short bf16x8;
typedef __attribute__((ext_vector_type(4))) float f32x4;

#define AS1 __attribute__((address_space(1)))
#define AS3 __attribute__((address_space(3)))

static __device__ __forceinline__ u16 f2b(float f) {
  u32 u = __float_as_uint(f);
  return (u16)((u + 0x7FFFu + ((u >> 16) & 1u)) >> 16);
}
static __device__ __forceinline__ u16 f2b_fast(float f) {   // round-half-up
  return (u16)((__float_as_uint(f) + 0x8000u) >> 16);
}
static __device__ __forceinline__ float b2f(u16 b) {
  return __uint_as_float(((u32)b) << 16);
}

// ---------------------------------------------------------------------------
// prep: cast x (4096x1024) -> bf16; P (2048x64) -> bf16 (+ guard row 2048);
//       W (1024x3072) -> Wt bf16 TRANSPOSED [3072][1024] via LDS tiles.
// ---------------------------------------------------------------------------
__global__ __launch_bounds__(256) void prep(
    const float* __restrict__ x, const float* __restrict__ W,
    const float* __restrict__ P,
    u16* __restrict__ xb, u16* __restrict__ Wt, u16* __restrict__ Pb)
{
  __shared__ u16 sT[64 * 68];
  const int bid = blockIdx.x, t = threadIdx.x;
  if (bid < 4096) {
    const size_t base = (size_t)bid * 1024 + t * 4;
    const float4 v = *(const float4*)(x + base);
    const u32 lo = (u32)f2b(v.x) | ((u32)f2b(v.y) << 16);
    const u32 hi = (u32)f2b(v.z) | ((u32)f2b(v.w) << 16);
    *(uint2*)(xb + base) = make_uint2(lo, hi);
  } else if (bid < 4224) {
    const size_t base = (size_t)(bid - 4096) * 1024 + t * 4;
    const float4 v = *(const float4*)(P + base);
    const u32 lo = (u32)f2b(v.x) | ((u32)f2b(v.y) << 16);
    const u32 hi = (u32)f2b(v.z) | ((u32)f2b(v.w) << 16);
    *(uint2*)(Pb + base) = make_uint2(lo, hi);
  } else if (bid < 4992) {
    const int tb = bid - 4224;
    const int tk = tb / 48, tn = tb % 48;
    const int k0 = tk * 64, n0 = tn * 64;
#pragma unroll
    for (int it = 0; it < 4; ++it) {
      const int c = it * 256 + t;
      const int r = c >> 4, c4 = (c & 15) << 2;
      const float4 v = *(const float4*)(W + (size_t)(k0 + r) * 3072 + n0 + c4);
      sT[(c4 + 0) * 68 + r] = f2b(v.x);
      sT[(c4 + 1) * 68 + r] = f2b(v.y);
      sT[(c4 + 2) * 68 + r] = f2b(v.z);
      sT[(c4 + 3) * 68 + r] = f2b(v.w);
    }
    __syncthreads();
#pragma unroll
    for (int it = 0; it < 4; ++it) {
      const int c = it * 256 + t;
      const int rr = c >> 4, k4 = (c & 15) << 2;
      const uint2 rv = *(const uint2*)(sT + rr * 68 + k4);
      *(uint2*)(Wt + (size_t)(n0 + rr) * 1024 + k0 + k4) = rv;
    }
  } else {
    if (t < 64) Pb[2048 * 64 + t] = f2b(P[2047 * 64 + t]);  // guard row
  }
}

// ---------------------------------------------------------------------------
// qkv_gemm (bf16 MFMA): C = xb(4096x1024) @ Wt^T(1024x3072) + bias.
// 128x128 tile, BK=64, XOR-swizzled LDS, global_load_lds 16B, XCD-aware grid.
// Epilogue: LDS repack -> coalesced stores; V transposed via Tv tile.
// ---------------------------------------------------------------------------
__global__ __launch_bounds__(256, 3) void qkv_gemm(
    const u16* __restrict__ xb, const u16* __restrict__ Wt,
    const float* __restrict__ bq,
    u16* __restrict__ Qh, u16* __restrict__ Kh, u16* __restrict__ Vt)
{
  __shared__ u16 smem[16384];        // 32 KB: sA | sB, reused as repack tile
  u16* const sA = smem;
  u16* const sB = smem + 8192;
  u16* const T  = smem;              // epilogue tile [64][136] (Q/K)
  u16* const Tv = smem;              // epilogue tile [128][72] (V, transposed)
  const int t = threadIdx.x;
  const int lane = t & 63, w = t >> 6;
  const int l = lane & 15, ql = lane >> 4;
  const int wm = w & 1, wn = w >> 1;
  const int vid = blockIdx.x;
  const int xcd = vid & 7, jj = vid >> 3;          // jj in [0,96)
  const int n0 = (xcd * 3 + (jj % 3)) * 128;
  const int m0 = (jj / 3) * 128;

  f32x4 acc[4][4];
#pragma unroll
  for (int i = 0; i < 4; ++i)
#pragma unroll
    for (int j = 0; j < 4; ++j) acc[i][j] = (f32x4){0.f, 0.f, 0.f, 0.f};

  for (int k0 = 0; k0 < 1024; k0 += 64) {
    __syncthreads();
#pragma unroll
    for (int j = 0; j < 4; ++j) {
      const int ii = w * 4 + j;
      const int m = ii * 8 + (lane >> 3);
      const int q8 = (lane & 7) ^ (m & 7);
      __builtin_amdgcn_global_load_lds(
          (const AS1 u32*)(xb + (size_t)(m0 + m) * 1024 + k0 + q8 * 8),
          (AS3 u32*)(sA + ii * 512), 16, 0, 0);
      __builtin_amdgcn_global_load_lds(
          (const AS1 u32*)(Wt + (size_t)(n0 + m) * 1024 + k0 + q8 * 8),
          (AS3 u32*)(sB + ii * 512), 16, 0, 0);
    }
    __syncthreads();
#pragma unroll
    for (int ks = 0; ks < 2; ++ks) {
      bf16x8 a[4], b[4];
#pragma unroll
      for (int mt = 0; mt < 4; ++mt) {
        const int m = wm * 64 + mt * 16 + l;
        a[mt] = *(const bf16x8*)(sA + m * 64 + (((ks * 4 + ql) ^ (m & 7)) * 8));
      }
#pragma unroll
      for (int nt = 0; nt < 4; ++nt) {
        const int nn = wn * 64 + nt * 16 + l;
        b[nt] = *(const bf16x8*)(sB + nn * 64 + (((ks * 4 + ql) ^ (nn & 7)) * 8));
      }
#pragma unroll
      for (int mt = 0; mt < 4; ++mt)
#pragma unroll
        for (int nt = 0; nt < 4; ++nt)
          acc[mt][nt] = __builtin_amdgcn_mfma_f32_16x16x32_bf16(
              a[mt], b[nt], acc[mt][nt], 0, 0, 0);
    }
  }

  const int which = n0 >> 10;                 // 0=Q 1=K 2=V (uniform per block)
  const int qbase = m0 & 1023;
  const int bb = m0 >> 10;
  const int h0 = (n0 & 1023) >> 6;
#pragma unroll
  for (int pass = 0; pass < 2; ++pass) {
    __syncthreads();
    if (which < 2) {
      if (wm == pass) {
#pragma unroll
        for (int nt = 0; nt < 4; ++nt) {
          const int col = wn * 64 + nt * 16 + l;
          const float bias = bq[n0 + col];
#pragma unroll
          for (int mt = 0; mt < 4; ++mt)
#pragma unroll
            for (int rg = 0; rg < 4; ++rg)
              T[(mt * 16 + ql * 4 + rg) * 136 + col] = f2b(acc[mt][nt][rg] + bias);
        }
      }
      __syncthreads();
      u16* const dst = which ? Kh : Qh;
#pragma unroll
      for (int h = 0; h < 2; ++h) {
        const size_t bnoff = ((size_t)(bb * 16 + h0 + h)) << 16;
#pragma unroll
        for (int it = 0; it < 2; ++it) {
          const int c = it * 256 + t;
          const int r = c >> 3, d8 = (c & 7) * 8;
          const uint4 v = *(const uint4*)(T + r * 136 + h * 64 + d8);
          *(uint4*)(dst + bnoff + ((size_t)(qbase + pass * 64 + r) << 6) + d8) = v;
        }
      }
    } else {
      // V: transposed repack tile Tv[col=128][row=64], pitch 72 (16B-aligned)
      if (wm == pass) {
#pragma unroll
        for (int nt = 0; nt < 4; ++nt) {
          const int col = wn * 64 + nt * 16 + l;
          const float bias = bq[n0 + col];
#pragma unroll
          for (int mt = 0; mt < 4; ++mt) {
            const u32 lo = (u32)f2b(acc[mt][nt][0] + bias) |
                           ((u32)f2b(acc[mt][nt][1] + bias) << 16);
            const u32 hi = (u32)f2b(acc[mt][nt][2] + bias) |
                           ((u32)f2b(acc[mt][nt][3] + bias) << 16);
            *(uint2*)(Tv + col * 72 + mt * 16 + ql * 4) = make_uint2(lo, hi);
          }
        }
      }
      __syncthreads();
#pragma unroll
      for (int h = 0; h < 2; ++h) {
        const size_t bnoff = ((size_t)(bb * 16 + h0 + h)) << 16;
#pragma unroll
        for (int it = 0; it < 2; ++it) {
          const int c = it * 256 + t;
          const int dr = c >> 3, q8 = (c & 7) * 8;
          const uint4 v = *(const uint4*)(Tv + (h * 64 + dr) * 72 + q8);
          *(uint4*)(Vt + bnoff + ((size_t)dr << 10) + qbase + pass * 64 + q8) = v;
        }
      }
    }
  }
}

// ---------------------------------------------------------------------------
// rel_attn (bf16 MFMA flash, no-max softmax), SOFTWARE-PIPELINED this round:
// body(k) = { barrier; issue DMA K/P[k+2],V[k+1]; softmax(k) on z computed
// LAST body; per ks: prob-write(k), z(k+1) half, PV(k) half }.
// Softmax never waits on fresh MFMA results (acc-read stall removed) and the
// z(k+1) MFMA+ds_read stream sits between prob-write(k) and PV(k), covering
// the prob LDS round-trip. Single z-register bank: z(k) dies in softmax(k)
// before z(k+1) is born. Hazards at the new distances (all gated by the one
// barrier/iter): K buf k&1 (target of K[k+2]) last read by z(k) in body(k-1);
// ring quadrant [rb,rb+63] (target of P[k+2] rows) last read by z2(k) in
// body(k-1), disjoint from z2(k+1)'s [rb+64,rb+255]; V buf (k+1)&1 last read
// by PV(k-1). Ring pos === global row mod 8, swizzle keys preserved.
// ---------------------------------------------------------------------------
__global__ __launch_bounds__(256, 2) void rel_attn(
    const u16* __restrict__ Qh, const u16* __restrict__ Kh,
    const u16* __restrict__ Vt, const u16* __restrict__ Pb,
    const float* __restrict__ rrb, const float* __restrict__ rwb,
    float* __restrict__ out)
{
  __shared__ u16 smem[36864];        // 73728 B
  u16* const sK    = smem;           // [2][64][64] swizzled, double-buffered
  u16* const sVT   = smem + 8192;    // [2][64][64] swizzled (rows=d, cols=j)
  u16* const sPr   = smem + 16384;   // [256][64]   P ring, 64-row quadrants
  u16* const sProb = smem + 32768;   // [128][32]   swizzled half-tile
  u16* const sU    = smem;           // transient alias [128][64]
  u16* const sW    = smem + 16384;   // transient alias [128][64]

  const int t = threadIdx.x;
  const int lane = t & 63, w = t >> 6;
  const int l = lane & 15, ql = lane >> 4;
  const int vid = blockIdx.x;
  const int qt = vid >> 6, bn = vid & 63;          // vid&7 == bn&7 (XCD)
  const int n = bn & 15, bb = bn >> 4;
  const size_t hoff = (size_t)bn << 16;
  const int q0 = qt << 7;
  const int bz = 6 - 2 * w;                        // z2 rel-tile base

  // stage U = Q+rr, W = Q+rw+K (128 query rows), swizzled pitch-64
#pragma unroll
  for (int it = 0; it < 4; ++it) {
    const int c = it * 256 + t;
    const int i = c >> 3, ch = c & 7;
    const int d8 = ch * 8;
    const uint4 qv = *(const uint4*)(Qh + hoff + ((size_t)(q0 + i) << 6) + d8);
    const uint4 kv = *(const uint4*)(Kh + hoff + ((size_t)(q0 + i) << 6) + d8);
    const u16* qp = (const u16*)&qv;
    const u16* kp = (const u16*)&kv;
    u16 uo[8], wo[8];
#pragma unroll
    for (int e = 0; e < 8; ++e) {
      const float rv = rrb[n * 64 + d8 + e];
      const float wv = rwb[n * 64 + d8 + e];
      const float qf = b2f(qp[e]), kf = b2f(kp[e]);
      uo[e] = f2b(qf + rv);
      wo[e] = f2b(qf + wv + kf);
    }
    const int pos = i * 64 + ((ch ^ (i & 7)) * 8);
    *(uint4*)(sU + pos) = *(const uint4*)uo;
    *(uint4*)(sW + pos) = *(const uint4*)wo;
  }
  __syncthreads();

  bf16x8 au[2][2], aw[2][2];         // [mt][ks], loop-invariant A-frags
#pragma unroll
  for (int mt = 0; mt < 2; ++mt)
#pragma unroll
    for (int ks = 0; ks < 2; ++ks) {
      const int row = w * 32 + mt * 16 + l;
      const int off = row * 64 + (((ks * 4 + ql) ^ (row & 7)) * 8);
      au[mt][ks] = *(const bf16x8*)(sU + off);
      aw[mt][ks] = *(const bf16x8*)(sW + off);
    }
  __syncthreads();   // all frag reads done before DMA overwrites sU/sW region

  // prologue staging: K0->buf0, K1->buf1, V0->vbuf0, FULL 256-row P ring
  {
#pragma unroll
    for (int b = 0; b < 2; ++b)
#pragma unroll
      for (int j = 0; j < 2; ++j) {
        const int ii = w * 2 + j;
        const int m = ii * 8 + (lane >> 3);
        const int q8 = (lane & 7) ^ (m & 7);
        __builtin_amdgcn_global_load_lds(
            (const AS1 u32*)(Kh + hoff + ((size_t)(b * 64 + m) << 6) + q8 * 8),
            (AS3 u32*)(sK + b * 4096 + ii * 512), 16, 0, 0);
      }
#pragma unroll
    for (int j = 0; j < 2; ++j) {
      const int ii = w * 2 + j;
      const int m = ii * 8 + (lane >> 3);
      const int q8 = (lane & 7) ^ (m & 7);
      __builtin_amdgcn_global_load_lds(
          (const AS1 u32*)(Vt + hoff + ((size_t)m << 10) + q8 * 8),
          (AS3 u32*)(sVT + ii * 512), 16, 0, 0);
    }
    const int lbase0 = 897 - q0;
    const int rb0 = (896 - q0) & 255;
#pragma unroll
    for (int j = 0; j < 8; ++j) {
      const int ii = w * 8 + j;
      const int m = ii * 8 + (lane >> 3);
      const int q8 = (lane & 7) ^ (m & 7);
      __builtin_amdgcn_global_load_lds(
          (const AS1 u32*)(Pb + ((size_t)(lbase0 + m) << 6) + q8 * 8),
          (AS3 u32*)(sPr + ((rb0 + ii * 8) & 255) * 64), 16, 0, 0);
    }
  }
  __syncthreads();   // all prologue tiles resident

  const f32x4 Z0 = (f32x4){0.f, 0.f, 0.f, 0.f};
  f32x4 z1[2][4], z2[2][5];
  // z-half compute for K-tile kk: z1 += U.K^T, z2 += W.Pband^T (one ks half)
  auto zhalf = [&](int kk, int ks, bool first) {
    const u16* const cK = sK + (kk & 1) * 4096;
    const int rbk = (896 + (kk << 6) - q0) & 255;
#pragma unroll
    for (int nt = 0; nt < 4; ++nt) {
      const int row = nt * 16 + l;
      const bf16x8 bk =
          *(const bf16x8*)(cK + row * 64 + (((ks * 4 + ql) ^ (row & 7)) * 8));
#pragma unroll
      for (int mt = 0; mt < 2; ++mt)
        z1[mt][nt] = __builtin_amdgcn_mfma_f32_16x16x32_bf16(
            au[mt][ks], bk, first ? Z0 : z1[mt][nt], 0, 0, 0);
    }
#pragma unroll
    for (int rt = 0; rt < 6; ++rt) {
      const int row = (bz + rt) * 16 + l;
      const bf16x8 bp = *(const bf16x8*)(
          sPr + ((rbk + row) & 255) * 64 + (((ks * 4 + ql) ^ (row & 7)) * 8));
      if (rt >= 1)
        z2[0][rt - 1] = __builtin_amdgcn_mfma_f32_16x16x32_bf16(
            aw[0][ks], bp, first ? Z0 : z2[0][rt - 1], 0, 0, 0);
      if (rt <= 4)
        z2[1][rt] = __builtin_amdgcn_mfma_f32_16x16x32_bf16(
            aw[1][ks], bp, first ? Z0 : z2[1][rt], 0, 0, 0);
    }
  };
  zhalf(0, 0, true);
  zhalf(0, 1, false);

  f32x4 o[2][4];
  float lrun[2][4];
#pragma unroll
  for (int mt = 0; mt < 2; ++mt)
#pragma unroll
    for (int ii = 0; ii < 4; ++ii) {
      o[mt][ii] = (f32x4){0.f, 0.f, 0.f, 0.f};
      lrun[mt][ii] = 0.f;
    }

  for (int k = 0; k < 16; ++k) {
    const int k0 = k << 6;
    __syncthreads();   // drains own DMA: K/P[k+1] (from body k-1), V[k] in

    const int rbk = (896 + k0 - q0) & 255;   // ring base of band k
    if (k <= 13) {     // K[k+2] -> buf k&1; P[k+2]'s 64 new rows -> [rb,rb+63]
#pragma unroll
      for (int j = 0; j < 2; ++j) {
        const int ii = w * 2 + j;
        const int m = ii * 8 + (lane >> 3);
        const int q8 = (lane & 7) ^ (m & 7);
        __builtin_amdgcn_global_load_lds(
            (const AS1 u32*)(Kh + hoff + ((size_t)(k0 + 128 + m) << 6) + q8 * 8),
            (AS3 u32*)(sK + (k & 1) * 4096 + ii * 512), 16, 0, 0);
        __builtin_amdgcn_global_load_lds(
            (const AS1 u32*)(Pb + ((size_t)(897 + k0 + 256 - q0 + m) << 6) + q8 * 8),
            (AS3 u32*)(sPr + ((rbk + ii * 8) & 255) * 64), 16, 0, 0);
      }
    }
    if (k <= 14) {     // V[k+1] -> vbuf (k+1)&1
#pragma unroll
      for (int j = 0; j < 2; ++j) {
        const int ii = w * 2 + j;
        const int m = ii * 8 + (lane >> 3);
        const int q8 = (lane & 7) ^ (m & 7);
        __builtin_amdgcn_global_load_lds(
            (const AS1 u32*)(Vt + hoff + ((size_t)m << 10) + k0 + 64 + q8 * 8),
            (AS3 u32*)(sVT + ((k + 1) & 1) * 4096 + ii * 512), 16, 0, 0);
      }
    }

    // softmax(k): diagonal gather + exp2 on z (computed last body -> no stall)
    float p[2][4][4];
#pragma unroll
    for (int mt = 0; mt < 2; ++mt)
#pragma unroll
      for (int ii = 0; ii < 4; ++ii) {
        const int ci = 15 - ql * 4 - ii;               // c' & 15
        const int src = (lane & 48) | ((l + ci) & 15);
        const bool wrap = l < ci;
#pragma unroll
        for (int jt = 0; jt < 4; ++jt) {
          const float val = wrap ? z2[mt][jt + 1][ii] : z2[mt][jt][ii];
          const float g = __shfl(val, src, 64);
          const float pv =
              __builtin_amdgcn_exp2f((z1[mt][jt][ii] + g) * 0.18033688011112042f);
          p[mt][ii][jt] = pv;
          lrun[mt][ii] += pv;
        }
      }

    // per ks: prob-write(k) -> z(k+1) half (covers prob lgkm) -> PV(k) half
    const u16* const cV = sVT + (k & 1) * 4096;
#pragma unroll
    for (int ks = 0; ks < 2; ++ks) {
#pragma unroll
      for (int mt = 0; mt < 2; ++mt)
#pragma unroll
        for (int ii = 0; ii < 4; ++ii) {
          const int r = w * 32 + mt * 16 + ql * 4 + ii;
          const int sw2 = (r & 3) ^ ((r >> 2) & 3);
#pragma unroll
          for (int jh = 0; jh < 2; ++jh) {
            const int ch = jh * 2 + (l >> 3);
            sProb[r * 32 + ((ch ^ sw2) * 8) + (l & 7)] =
                f2b_fast(p[mt][ii][ks * 2 + jh]);
          }
        }
      if (k < 15) {
        __builtin_amdgcn_s_setprio(1);
        zhalf(k + 1, ks, ks == 0);
        __builtin_amdgcn_s_setprio(0);
      }
      bf16x8 bv[4];
#pragma unroll
      for (int dt = 0; dt < 4; ++dt) {
        const int row = dt * 16 + l;
        bv[dt] =
            *(const bf16x8*)(cV + row * 64 + (((ks * 4 + ql) ^ (row & 7)) * 8));
      }
      __builtin_amdgcn_s_setprio(1);
#pragma unroll
      for (int mt = 0; mt < 2; ++mt) {
        const int ar = w * 32 + mt * 16 + l;
        const bf16x8 ap = *(const bf16x8*)(
            sProb + ar * 32 + ((ql ^ ((ar & 3) ^ ((ar >> 2) & 3))) * 8));
#pragma unroll
        for (int dt = 0; dt < 4; ++dt)
          o[mt][dt] = __builtin_amdgcn_mfma_f32_16x16x32_bf16(
              ap, bv[dt], o[mt][dt], 0, 0, 0);
      }
      __builtin_amdgcn_s_setprio(0);
    }
  }

  // epilogue: row-sum reduce, normalize, store fp32 (B, L, D)
#pragma unroll
  for (int mt = 0; mt < 2; ++mt)
#pragma unroll
    for (int ii = 0; ii < 4; ++ii) {
      float ls = lrun[mt][ii];
      ls += __shfl_xor(ls, 1);
      ls += __shfl_xor(ls, 2);
      ls += __shfl_xor(ls, 4);
      ls += __shfl_xor(ls, 8);
      const float inv = 1.f / ls;
      const int q = q0 + w * 32 + mt * 16 + ql * 4 + ii;
#pragma unroll
      for (int dt = 0; dt < 4; ++dt)
        out[((size_t)(bb * 1024 + q) << 10) + (n << 6) + dt * 16 + l] =
            o[mt][dt][ii] * inv;
    }
}

// ---------------------------------------------------------------------------
extern "C" void kernel_launch(void* const* d_in, const int* in_sizes, int n_in,
                              void* d_out, int out_size, void* d_ws, size_t ws_size,
                              hipStream_t stream) {
  const float* x  = (const float*)d_in[0];  // (4,1024,1024)
  const float* P  = (const float*)d_in[1];  // (2048,64)
  const float* Wq = (const float*)d_in[2];  // (1024,3072)
  const float* bq = (const float*)d_in[3];  // (3072,)
  const float* rr = (const float*)d_in[4];  // (16,64)
  const float* rw = (const float*)d_in[5];  // (16,64)
  float* out = (float*)d_out;

  char* ws = (char*)d_ws;
  u16* xb = (u16*)(ws);                      // 8 MB
  u16* Wt = (u16*)(ws + 8388608);            // 6 MB  [3072][1024]
  u16* Pb = (u16*)(ws + 14680064);           // 2049 rows x 64 (+guard)
  u16* Qh = (u16*)(ws + 14946304);           // 8 MB  [bn][q][d]
  u16* Kh = (u16*)(ws + 23334912);           // 8 MB
  u16* Vt = (u16*)(ws + 31723520);           // 8 MB  [bn][d][q]

  prep<<<4993, 256, 0, stream>>>(x, Wq, P, xb, Wt, Pb);
  qkv_gemm<<<768, 256, 0, stream>>>(xb, Wt, bq, Qh, Kh, Vt);
  rel_attn<<<512, 256, 0, stream>>>(Qh, Kh, Vt, Pb, rr, rw, out);
}